// Round 11
// baseline (180.234 us; speedup 1.0000x reference)
//
#include <hip/hip_runtime.h>

// MHA forward, MI355X/gfx950, bf16 MFMA pipeline. Round 12.
// x:[2,2048,1024] f32; w_q/k/v/o:[1024,1024] f32 (nn.Linear: y = x @ W^T)
// out:[2,2048,1024] f32.
//
// Round-12 change (vs R10 178.4, best):
//  - attn: softmax denominator via MATRIX pipe: oaccL = mfma(P_frag, ones)
//    accumulates l[row] = sum_k P[row][k] (key permutation irrelevant to a
//    row sum). Removes 16-32 dependent v_add per step from the VALU stream
//    and the entire epilogue shuffle-reduce (l lands per-lane at [r]).
//    l now sums the same bf16-rounded p used in the PV numerator.
//  - Everything else identical to R10 (3-buffer counted-vmcnt attn pipeline,
//    V^T key-permuted, exp2-folded softmax, R5 gemms).

typedef __bf16 bf16x8 __attribute__((ext_vector_type(8)));
typedef float f32x4 __attribute__((ext_vector_type(4)));
typedef unsigned short u16;
typedef unsigned int u32;
typedef u32 u32x4 __attribute__((ext_vector_type(4)));

#define S_LEN 2048
#define NH 16
#define DHD 64
#define QK_PRESCALE 0.18033688011112042f  // log2(e)/8, folded into W_q
#define SOFTMAX_M2 17.312340489667652f    // 12 * log2(e); scores |s/8|<~7

__device__ __forceinline__ u16 f2bf(float f) {
  unsigned u = __float_as_uint(f);
  u += 0x7fffu + ((u >> 16) & 1u);  // RNE
  return (u16)(u >> 16);
}

__device__ __forceinline__ u32 cvtpk(float lo, float hi) {
  u32 r;
  asm("v_cvt_pk_bf16_f32 %0, %1, %2" : "=v"(r) : "v"(lo), "v"(hi));
  return r;
}

__device__ __forceinline__ void gld_lds16(const void* g, void* l) {
  __builtin_amdgcn_global_load_lds(
      (const __attribute__((address_space(1))) void*)g,
      (__attribute__((address_space(3))) void*)l, 16, 0, 0);
}

// ---------------- fp32 -> bf16 convert, all 5 tensors in one launch --------
__global__ __launch_bounds__(256) void cvt_all(const float* __restrict__ x,
                                               const float* __restrict__ wq,
                                               const float* __restrict__ wk,
                                               const float* __restrict__ wv,
                                               const float* __restrict__ wo,
                                               u16* __restrict__ dst) {
  const int i = (blockIdx.x * 256 + threadIdx.x) * 4;
  const float* src;
  int off;
  float sc = 1.0f;
  if (i < (4 << 20))      { src = x;  off = 0; }
  else if (i < (5 << 20)) { src = wq; off = 4 << 20; sc = QK_PRESCALE; }
  else if (i < (6 << 20)) { src = wk; off = 5 << 20; }
  else if (i < (7 << 20)) { src = wv; off = 6 << 20; }
  else                    { src = wo; off = 7 << 20; }
  const float4 v = *(const float4*)(src + (i - off));
  *(ushort4*)(dst + i) =
      make_ushort4(f2bf(v.x * sc), f2bf(v.y * sc), f2bf(v.z * sc), f2bf(v.w * sc));
}

// ---------------- fused QKV projection GEMM --------------------------------
// Y[m, n_global] = sum_k A[m,k] * W[n,k], n_global in [0,3072).
// grid (24, 32). V^T stored with per-32 key permutation (R9-proven).
__global__ __launch_bounds__(256) void gemm_qkv(const u16* __restrict__ A,
                                                const u16* __restrict__ Wq,
                                                const u16* __restrict__ Wk,
                                                const u16* __restrict__ Wv,
                                                u16* __restrict__ Qo,
                                                u16* __restrict__ Ko,
                                                u16* __restrict__ Vo) {
  constexpr int K = 1024;
  __shared__ __align__(16) u16 Asm[2][128 * 32];
  __shared__ __align__(16) u16 Bsm[2][128 * 32];
  const int tid = threadIdx.x;
  const int wave = tid >> 6, lane = tid & 63;
  const int wm = wave >> 1, wn = wave & 1;
  const int quad = lane >> 4, l16 = lane & 15;
  const int m0 = blockIdx.y * 128;
  const int n0g = blockIdx.x * 128;
  const int wsel = n0g >> 10, n0 = n0g & 1023;
  const u16* Bw = (wsel == 0) ? Wq : (wsel == 1 ? Wk : Wv);
  u16* out = (wsel == 0) ? Qo : (wsel == 1 ? Ko : Vo);

  const u16* Ag = A + (size_t)(m0 + (lane >> 2)) * K + (lane & 3) * 8;
  const u16* Bg = Bw + (size_t)(n0 + (lane >> 2)) * K + (lane & 3) * 8;

  auto STAGE = [&](int buf, int k0) {
#pragma unroll
    for (int c = 0; c < 2; ++c) {
      const int rbase = wave * 32 + c * 16;
      gld_lds16(Ag + (size_t)rbase * K + k0, Asm[buf] + rbase * 32);
      gld_lds16(Bg + (size_t)rbase * K + k0, Bsm[buf] + rbase * 32);
    }
  };

  f32x4 acc[4][4] = {};
  STAGE(0, 0);
  __syncthreads();
  int cur = 0;
  for (int k0 = 0; k0 < K; k0 += 32) {
    if (k0 + 32 < K) STAGE(cur ^ 1, k0 + 32);
    bf16x8 af[4], bfv[4];
#pragma unroll
    for (int i = 0; i < 4; ++i)
      af[i] = *(const bf16x8*)(Asm[cur] + (wm * 64 + i * 16 + l16) * 32 + quad * 8);
#pragma unroll
    for (int j = 0; j < 4; ++j)
      bfv[j] = *(const bf16x8*)(Bsm[cur] + (wn * 64 + j * 16 + l16) * 32 + quad * 8);
#pragma unroll
    for (int i = 0; i < 4; ++i)
#pragma unroll
      for (int j = 0; j < 4; ++j)
        acc[i][j] = __builtin_amdgcn_mfma_f32_16x16x32_bf16(af[i], bfv[j],
                                                            acc[i][j], 0, 0, 0);
    __syncthreads();
    cur ^= 1;
  }

#pragma unroll
  for (int i = 0; i < 4; ++i) {
#pragma unroll
    for (int j = 0; j < 4; ++j) {
#pragma unroll
      for (int r = 0; r < 4; ++r) {
        const int m = m0 + wm * 64 + i * 16 + quad * 4 + r;
        const int n = n0 + wn * 64 + j * 16 + l16;
        const int b = m >> 11, s = m & 2047;
        const int h = n >> 6, dh = n & 63;
        const u16 v = f2bf(acc[i][j][r]);
        if (wsel < 2) {
          out[(((size_t)(b * NH + h)) * S_LEN + s) * DHD + dh] = v;
        } else {
          // key-permuted column: s5=[i0,q1,q0,r1,r0] -> pos=[q1,q0,i0,r1,r0]
          const int pos = (s & ~31) | (quad * 8 + (i & 1) * 4 + r);
          out[(((size_t)(b * NH + h)) * DHD + dh) * S_LEN + pos] = v;
        }
      }
    }
  }
}

// ---------------- output projection GEMM -> f32 (R5 form) ------------------
__global__ __launch_bounds__(256) void gemm_out(const u16* __restrict__ A,
                                                const u16* __restrict__ Bw,
                                                float* __restrict__ out) {
  constexpr int K = 1024, N = 1024;
  __shared__ __align__(16) u16 Asm[2][128 * 32];
  __shared__ __align__(16) u16 Bsm[2][128 * 32];
  const int tid = threadIdx.x;
  const int wave = tid >> 6, lane = tid & 63;
  const int wm = wave >> 1, wn = wave & 1;
  const int quad = lane >> 4, l16 = lane & 15;
  const int m0 = blockIdx.y * 128, n0 = blockIdx.x * 128;
  const u16* Ag = A + (size_t)(m0 + (lane >> 2)) * K + (lane & 3) * 8;
  const u16* Bg = Bw + (size_t)(n0 + (lane >> 2)) * K + (lane & 3) * 8;

  auto STAGE = [&](int buf, int k0) {
#pragma unroll
    for (int c = 0; c < 2; ++c) {
      const int rbase = wave * 32 + c * 16;
      gld_lds16(Ag + (size_t)rbase * K + k0, Asm[buf] + rbase * 32);
      gld_lds16(Bg + (size_t)rbase * K + k0, Bsm[buf] + rbase * 32);
    }
  };

  f32x4 acc[4][4] = {};
  STAGE(0, 0);
  __syncthreads();
  int cur = 0;
  for (int k0 = 0; k0 < K; k0 += 32) {
    if (k0 + 32 < K) STAGE(cur ^ 1, k0 + 32);
    bf16x8 af[4], bfv[4];
#pragma unroll
    for (int i = 0; i < 4; ++i)
      af[i] = *(const bf16x8*)(Asm[cur] + (wm * 64 + i * 16 + l16) * 32 + quad * 8);
#pragma unroll
    for (int j = 0; j < 4; ++j)
      bfv[j] = *(const bf16x8*)(Bsm[cur] + (wn * 64 + j * 16 + l16) * 32 + quad * 8);
#pragma unroll
    for (int i = 0; i < 4; ++i)
#pragma unroll
      for (int j = 0; j < 4; ++j)
        acc[i][j] = __builtin_amdgcn_mfma_f32_16x16x32_bf16(af[i], bfv[j],
                                                            acc[i][j], 0, 0, 0);
    __syncthreads();
    cur ^= 1;
  }
#pragma unroll
  for (int i = 0; i < 4; ++i)
#pragma unroll
    for (int j = 0; j < 4; ++j)
#pragma unroll
      for (int r = 0; r < 4; ++r) {
        const int m = m0 + wm * 64 + i * 16 + quad * 4 + r;
        const int n = n0 + wn * 64 + j * 16 + l16;
        out[(size_t)m * N + n] = acc[i][j][r];
      }
}

// ---------------- causal flash attention -----------------------------------
// R10 structure: pairing {i,31-i}, 3-buffer counted-vmcnt pipeline.
// l accumulated on the MATRIX pipe: oaccL = mfma(P_frag, ones) -> l[row]
// lands at oaccL[r] for q-row base+quad*4+r (replicated over l16).
__global__ __launch_bounds__(256, 2) void attn_kernel(const u16* __restrict__ Qw,
                                                      const u16* __restrict__ Kw,
                                                      const u16* __restrict__ Vw,
                                                      u16* __restrict__ Ow) {
  __shared__ __align__(16) u16 Ksm[3][64 * 64];   // K rows [key][dh], swizzled
  __shared__ __align__(16) u16 Vsm[3][64 * 64];   // Vt rows [dh][key*], swizzled
  const int tid = threadIdx.x;
  const int wave = tid >> 6, lane = tid & 63;
  const int quad = lane >> 4, l16 = lane & 15;
  const int flat = blockIdx.y * 16 + blockIdx.x;  // 512 blocks
  const int xcd = flat & 7, li = flat >> 3;       // li in 0..63
  const int bh = xcd * 4 + (li >> 4);
  const int pairi = li & 15;
  const int qtA = pairi, qtB = 31 - pairi;        // qtA < qtB always
  const u16* Q = Qw + (size_t)bh * S_LEN * DHD;
  const u16* Kp = Kw + (size_t)bh * S_LEN * DHD;
  const u16* Vp = Vw + (size_t)bh * DHD * S_LEN;
  const int b = bh >> 4, h = bh & 15;

  const int ss = ((lane & 7) ^ (lane >> 3)) * 8;
  const int ps0 = (quad ^ (l16 & 7)) * 8;
  const int ps1 = ps0 ^ 32;

  const int qrowA = qtA * 64 + wave * 16 + l16;
  const int qrowB = qtB * 64 + wave * 16 + l16;
  const bf16x8 aqA0 = *(const bf16x8*)(Q + (size_t)qrowA * DHD + quad * 8);
  const bf16x8 aqA1 = *(const bf16x8*)(Q + (size_t)qrowA * DHD + 32 + quad * 8);
  const bf16x8 aqB0 = *(const bf16x8*)(Q + (size_t)qrowB * DHD + quad * 8);
  const bf16x8 aqB1 = *(const bf16x8*)(Q + (size_t)qrowB * DHD + 32 + quad * 8);

  // all-ones bf16 fragment for the l row-sum MFMA
  const bf16x8 vones = __builtin_bit_cast(
      bf16x8, (u32x4){0x3F803F80u, 0x3F803F80u, 0x3F803F80u, 0x3F803F80u});

  f32x4 oaccA[4] = {}, oaccB[4] = {};
  f32x4 oaccLA = {}, oaccLB = {};

  auto stageKV = [&](int buf, int t) {
    const int k0 = t * 64;
#pragma unroll
    for (int c = 0; c < 2; ++c) {
      const int r0 = c * 32 + wave * 8;  // row&7 = lane>>3
      gld_lds16(Kp + (size_t)(k0 + r0 + (lane >> 3)) * DHD + ss,
                Ksm[buf] + r0 * 64);
      gld_lds16(Vp + (size_t)(r0 + (lane >> 3)) * S_LEN + k0 + ss,
                Vsm[buf] + r0 * 64);
    }
  };

  // sync macros: per-wave counted drain + cross-wave barrier, fenced (rule 18)
#define SYNC4                                                   \
  {                                                             \
    asm volatile("s_waitcnt vmcnt(4)" ::: "memory");            \
    __builtin_amdgcn_sched_barrier(0);                          \
    __builtin_amdgcn_s_barrier();                               \
    __builtin_amdgcn_sched_barrier(0);                          \
  }
#define SYNC0                                                   \
  {                                                             \
    asm volatile("s_waitcnt vmcnt(0)" ::: "memory");            \
    __builtin_amdgcn_sched_barrier(0);                          \
    __builtin_amdgcn_s_barrier();                               \
    __builtin_amdgcn_sched_barrier(0);                          \
  }
#define POST(T)                                                 \
  {                                                             \
    __builtin_amdgcn_sched_barrier(0);                          \
    __builtin_amdgcn_s_barrier();                               \
    __builtin_amdgcn_sched_barrier(0);                          \
    if ((T) + 2 <= qtB) {                                       \
      int nb = cur + 2; if (nb >= 3) nb -= 3;                   \
      stageKV(nb, (T) + 2);                                     \
    }                                                           \
    cur = (cur == 2) ? 0 : cur + 1;                             \
  }

  // One k-tile step. DOA/MA/MB are literal 0/1 (dead code eliminated).
#define STEP(T, DOA, MA, MB)                                                  \
  {                                                                           \
    const u16* Kc = Ksm[cur];                                                 \
    const u16* Vc = Vsm[cur];                                                 \
    f32x4 saccA[4], saccB[4];                                                 \
    _Pragma("unroll") for (int nt = 0; nt < 4; ++nt) {                        \
      const u16* krow = Kc + (nt * 16 + l16) * 64;                            \
      const bf16x8 kb0 = *(const bf16x8*)(krow + ps0);                        \
      const bf16x8 kb1 = *(const bf16x8*)(krow + ps1);                        \
      f32x4 zb = {};                                                          \
      zb = __builtin_amdgcn_mfma_f32_16x16x32_bf16(kb0, aqB0, zb, 0, 0, 0);   \
      zb = __builtin_amdgcn_mfma_f32_16x16x32_bf16(kb1, aqB1, zb, 0, 0, 0);   \
      saccB[nt] = zb;                                                         \
      if (DOA) {                                                              \
        f32x4 za = {};                                                        \
        za = __builtin_amdgcn_mfma_f32_16x16x32_bf16(kb0, aqA0, za, 0, 0, 0); \
        za = __builtin_amdgcn_mfma_f32_16x16x32_bf16(kb1, aqA1, za, 0, 0, 0); \
        saccA[nt] = za;                                                       \
      }                                                                       \
    }                                                                         \
    u32 pwB[8], pwA[8];                                                       \
    _Pragma("unroll") for (int nt = 0; nt < 4; ++nt) {                        \
      float p[4];                                                             \
      _Pragma("unroll") for (int r = 0; r < 4; ++r) {                         \
        float e = exp2f(saccB[nt][r] - SOFTMAX_M2);                           \
        if (MB) {                                                             \
          const int col = (T) * 64 + nt * 16 + quad * 4 + r;                  \
          e = (col <= qrowB) ? e : 0.f;                                       \
        }                                                                     \
        p[r] = e;                                                             \
      }                                                                       \
      pwB[nt * 2 + 0] = cvtpk(p[0], p[1]);                                    \
      pwB[nt * 2 + 1] = cvtpk(p[2], p[3]);                                    \
    }                                                                         \
    if (DOA) {                                                                \
      _Pragma("unroll") for (int nt = 0; nt < 4; ++nt) {                      \
        float p[4];                                                           \
        _Pragma("unroll") for (int r = 0; r < 4; ++r) {                       \
          float e = exp2f(saccA[nt][r] - SOFTMAX_M2);                         \
          if (MA) {                                                           \
            const int col = (T) * 64 + nt * 16 + quad * 4 + r;                \
            e = (col <= qrowA) ? e : 0.f;                                     \
          }                                                                   \
          p[r] = e;                                                           \
        }                                                                     \
        pwA[nt * 2 + 0] = cvtpk(p[0], p[1]);                                  \
        pwA[nt * 2 + 1] = cvtpk(p[2], p[3]);                                  \
      }                                                                       \
    }                                                                         \
    const bf16x8 paB0 =                                                       \
        __builtin_bit_cast(bf16x8, (u32x4){pwB[0], pwB[1], pwB[2], pwB[3]});  \
    const bf16x8 paB1 =                                                       \
        __builtin_bit_cast(bf16x8, (u32x4){pwB[4], pwB[5], pwB[6], pwB[7]});  \
    oaccLB = __builtin_amdgcn_mfma_f32_16x16x32_bf16(paB0, vones, oaccLB, 0, 0, 0); \
    oaccLB = __builtin_amdgcn_mfma_f32_16x16x32_bf16(paB1, vones, oaccLB, 0, 0, 0); \
    _Pragma("unroll") for (int nto = 0; nto < 4; ++nto) {                     \
      const u16* vrow = Vc + (nto * 16 + l16) * 64;                           \
      const bf16x8 bv0 = *(const bf16x8*)(vrow + ps0);                        \
      const bf16x8 bv1 = *(const bf16x8*)(vrow + ps1);                        \
      oaccB[nto] =                                                            \
          __builtin_amdgcn_mfma_f32_16x16x32_bf16(paB0, bv0, oaccB[nto], 0, 0, 0); \
      oaccB[nto] =                                                            \
          __builtin_amdgcn_mfma_f32_16x16x32_bf16(paB1, bv1, oaccB[nto], 0, 0, 0); \
      if (DOA) {                                                              \
        const bf16x8 paA0 = __builtin_bit_cast(                               \
            bf16x8, (u32x4){pwA[0], pwA[1], pwA[2], pwA[3]});                 \
        const bf16x8 paA1 = __builtin_bit_cast(                               \
            bf16x8, (u32x4){pwA[4], pwA[5], pwA[6], pwA[7]});                 \
        oaccA[nto] = __builtin_amdgcn_mfma_f32_16x16x32_bf16(paA0, bv0,       \
                                                             oaccA[nto], 0, 0, 0); \
        oaccA[nto] = __builtin_amdgcn_mfma_f32_16x16x32_bf16(paA1, bv1,       \
                                                             oaccA[nto], 0, 0, 0); \
      }                                                                       \
    }                                                                         \
    if (DOA) {                                                                \
      const bf16x8 paA0 = __builtin_bit_cast(                                 \
          bf16x8, (u32x4){pwA[0], pwA[1], pwA[2], pwA[3]});                   \
      const bf16x8 paA1 = __builtin_bit_cast(                                 \
          bf16x8, (u32x4){pwA[4], pwA[5], pwA[6], pwA[7]});                   \
      oaccLA = __builtin_amdgcn_mfma_f32_16x16x32_bf16(paA0, vones, oaccLA, 0, 0, 0); \
      oaccLA = __builtin_amdgcn_mfma_f32_16x16x32_bf16(paA1, vones, oaccLA, 0, 0, 0); \
    }                                                                         \
  }

  // prologue: stage tiles 0 and 1 (qtB >= 16, so both always exist)
  stageKV(0, 0);
  stageKV(1, 1);
  int cur = 0;
  int t = 0;
  for (; t < qtA; ++t) {                  // both tiles, no mask
    SYNC4
    STEP(t, 1, 0, 0)
    POST(t)
  }
  {                                       // t == qtA: A diagonal (qtA < qtB)
    SYNC4
    STEP(qtA, 1, 1, 0)
    POST(t)
    ++t;
  }
  for (; t < qtB; ++t) {                  // B only
    SYNC4
    STEP(t, 0, 0, 0)
    POST(t)
  }
  SYNC0                                   // final tile: full drain
  STEP(qtB, 0, 0, 1)
#undef STEP
#undef SYNC4
#undef SYNC0
#undef POST

  // epilogues -> [b, s, h, dh] bf16; l for q-row base+quad*4+r is oaccL[r]
#pragma unroll
  for (int r = 0; r < 4; ++r) {
    const float invA = 1.f / oaccLA[r];
    const float invB = 1.f / oaccLB[r];
    const int sA = qtA * 64 + wave * 16 + quad * 4 + r;
    const int sB = qtB * 64 + wave * 16 + quad * 4 + r;
#pragma unroll
    for (int nto = 0; nto < 4; ++nto) {
      const int dh = nto * 16 + l16;
      Ow[(((size_t)b * S_LEN + sA) * NH + h) * DHD + dh] = f2bf(oaccA[nto][r] * invA);
      Ow[(((size_t)b * S_LEN + sB) * NH + h) * DHD + dh] = f2bf(oaccB[nto][r] * invB);
    }
  }
}

extern "C" void kernel_launch(void* const* d_in, const int* in_sizes, int n_in,
                              void* d_out, int out_size, void* d_ws, size_t ws_size,
                              hipStream_t stream) {
  const float* x  = (const float*)d_in[0];
  const float* wq = (const float*)d_in[1];
  const float* wk = (const float*)d_in[2];
  const float* wv = (const float*)d_in[3];
  const float* wo = (const float*)d_in[4];
  float* out = (float*)d_out;
  char* ws = (char*)d_ws;
  const size_t MB = 1024 * 1024;
  u16* xb  = (u16*)(ws);             // 8 MB  [4096][1024] bf16
  u16* wqb = (u16*)(ws + 8 * MB);    // 2 MB
  u16* wkb = (u16*)(ws + 10 * MB);   // 2 MB
  u16* wvb = (u16*)(ws + 12 * MB);   // 2 MB
  u16* wob = (u16*)(ws + 14 * MB);   // 2 MB
  u16* qws = (u16*)(ws + 16 * MB);   // 8 MB  [b,h,s,dh]
  u16* kws = (u16*)(ws + 24 * MB);   // 8 MB  [b,h,s,dh]
  u16* vws = (u16*)(ws + 32 * MB);   // 8 MB  [b,h,dh,s*] (key-permuted)
  u16* aws = (u16*)(ws + 40 * MB);   // 8 MB  [b,s,h,dh]

  cvt_all<<<8192, 256, 0, stream>>>(x, wq, wk, wv, wo, xb);
  gemm_qkv<<<dim3(24, 32), 256, 0, stream>>>(xb, wqb, wkb, wvb, qws, kws, vws);
  attn_kernel<<<dim3(16, 32), 256, 0, stream>>>(qws, kws, vws, aws);
  gemm_out<<<dim3(8, 32), 256, 0, stream>>>(aws, wob, out);
}

// Round 12
// 180.168 us; speedup vs baseline: 1.0004x; 1.0004x over previous
//
#include <hip/hip_runtime.h>

// MHA forward, MI355X/gfx950, bf16 MFMA pipeline. Round 13.
// x:[2,2048,1024] f32; w_q/k/v/o:[1024,1024] f32 (nn.Linear: y = x @ W^T)
// out:[2,2048,1024] f32.
//
// Round-13 change (vs R10 178.4 best; R11 mfma-l reverted as regression):
//  - attn: WAVE-SPLIT pairing. 512-thread blocks; waves 0-3 own q-tile A
//    (=pairi), waves 4-7 own q-tile B (=31-pairi). Per-wave step body is the
//    proven single-tile macro; A and B chains now run CONCURRENTLY on
//    different SIMDs instead of serially within one wave. Block time
//    (qtA+1)*T_dbl+(qtB-qtA)*T_sgl (~34 T_s) -> (qtB+1)*T_sgl (17..32).
//    Shared K/V staging: 8 waves x 8 rows; 2-buffer prefetch-before-compute.
//  - gemm_qkv/gemm_out/cvt: R10 forms (V^T key-permuted, exp2-folded softmax,
//    128x128 gemm_out). l via VALU l4 + shuffle reduce (R10 form).

typedef __bf16 bf16x8 __attribute__((ext_vector_type(8)));
typedef float f32x4 __attribute__((ext_vector_type(4)));
typedef unsigned short u16;
typedef unsigned int u32;
typedef u32 u32x4 __attribute__((ext_vector_type(4)));

#define S_LEN 2048
#define NH 16
#define DHD 64
#define QK_PRESCALE 0.18033688011112042f  // log2(e)/8, folded into W_q
#define SOFTMAX_M2 17.312340489667652f    // 12 * log2(e); scores |s/8|<~7

__device__ __forceinline__ u16 f2bf(float f) {
  unsigned u = __float_as_uint(f);
  u += 0x7fffu + ((u >> 16) & 1u);  // RNE
  return (u16)(u >> 16);
}

__device__ __forceinline__ u32 cvtpk(float lo, float hi) {
  u32 r;
  asm("v_cvt_pk_bf16_f32 %0, %1, %2" : "=v"(r) : "v"(lo), "v"(hi));
  return r;
}

__device__ __forceinline__ void gld_lds16(const void* g, void* l) {
  __builtin_amdgcn_global_load_lds(
      (const __attribute__((address_space(1))) void*)g,
      (__attribute__((address_space(3))) void*)l, 16, 0, 0);
}

// ---------------- fp32 -> bf16 convert, all 5 tensors in one launch --------
__global__ __launch_bounds__(256) void cvt_all(const float* __restrict__ x,
                                               const float* __restrict__ wq,
                                               const float* __restrict__ wk,
                                               const float* __restrict__ wv,
                                               const float* __restrict__ wo,
                                               u16* __restrict__ dst) {
  const int i = (blockIdx.x * 256 + threadIdx.x) * 4;
  const float* src;
  int off;
  float sc = 1.0f;
  if (i < (4 << 20))      { src = x;  off = 0; }
  else if (i < (5 << 20)) { src = wq; off = 4 << 20; sc = QK_PRESCALE; }
  else if (i < (6 << 20)) { src = wk; off = 5 << 20; }
  else if (i < (7 << 20)) { src = wv; off = 6 << 20; }
  else                    { src = wo; off = 7 << 20; }
  const float4 v = *(const float4*)(src + (i - off));
  *(ushort4*)(dst + i) =
      make_ushort4(f2bf(v.x * sc), f2bf(v.y * sc), f2bf(v.z * sc), f2bf(v.w * sc));
}

// ---------------- fused QKV projection GEMM --------------------------------
// Y[m, n_global] = sum_k A[m,k] * W[n,k], n_global in [0,3072).
// grid (24, 32). V^T stored with per-32 key permutation (R9-proven).
__global__ __launch_bounds__(256) void gemm_qkv(const u16* __restrict__ A,
                                                const u16* __restrict__ Wq,
                                                const u16* __restrict__ Wk,
                                                const u16* __restrict__ Wv,
                                                u16* __restrict__ Qo,
                                                u16* __restrict__ Ko,
                                                u16* __restrict__ Vo) {
  constexpr int K = 1024;
  __shared__ __align__(16) u16 Asm[2][128 * 32];
  __shared__ __align__(16) u16 Bsm[2][128 * 32];
  const int tid = threadIdx.x;
  const int wave = tid >> 6, lane = tid & 63;
  const int wm = wave >> 1, wn = wave & 1;
  const int quad = lane >> 4, l16 = lane & 15;
  const int m0 = blockIdx.y * 128;
  const int n0g = blockIdx.x * 128;
  const int wsel = n0g >> 10, n0 = n0g & 1023;
  const u16* Bw = (wsel == 0) ? Wq : (wsel == 1 ? Wk : Wv);
  u16* out = (wsel == 0) ? Qo : (wsel == 1 ? Ko : Vo);

  const u16* Ag = A + (size_t)(m0 + (lane >> 2)) * K + (lane & 3) * 8;
  const u16* Bg = Bw + (size_t)(n0 + (lane >> 2)) * K + (lane & 3) * 8;

  auto STAGE = [&](int buf, int k0) {
#pragma unroll
    for (int c = 0; c < 2; ++c) {
      const int rbase = wave * 32 + c * 16;
      gld_lds16(Ag + (size_t)rbase * K + k0, Asm[buf] + rbase * 32);
      gld_lds16(Bg + (size_t)rbase * K + k0, Bsm[buf] + rbase * 32);
    }
  };

  f32x4 acc[4][4] = {};
  STAGE(0, 0);
  __syncthreads();
  int cur = 0;
  for (int k0 = 0; k0 < K; k0 += 32) {
    if (k0 + 32 < K) STAGE(cur ^ 1, k0 + 32);
    bf16x8 af[4], bfv[4];
#pragma unroll
    for (int i = 0; i < 4; ++i)
      af[i] = *(const bf16x8*)(Asm[cur] + (wm * 64 + i * 16 + l16) * 32 + quad * 8);
#pragma unroll
    for (int j = 0; j < 4; ++j)
      bfv[j] = *(const bf16x8*)(Bsm[cur] + (wn * 64 + j * 16 + l16) * 32 + quad * 8);
#pragma unroll
    for (int i = 0; i < 4; ++i)
#pragma unroll
      for (int j = 0; j < 4; ++j)
        acc[i][j] = __builtin_amdgcn_mfma_f32_16x16x32_bf16(af[i], bfv[j],
                                                            acc[i][j], 0, 0, 0);
    __syncthreads();
    cur ^= 1;
  }

#pragma unroll
  for (int i = 0; i < 4; ++i) {
#pragma unroll
    for (int j = 0; j < 4; ++j) {
#pragma unroll
      for (int r = 0; r < 4; ++r) {
        const int m = m0 + wm * 64 + i * 16 + quad * 4 + r;
        const int n = n0 + wn * 64 + j * 16 + l16;
        const int b = m >> 11, s = m & 2047;
        const int h = n >> 6, dh = n & 63;
        const u16 v = f2bf(acc[i][j][r]);
        if (wsel < 2) {
          out[(((size_t)(b * NH + h)) * S_LEN + s) * DHD + dh] = v;
        } else {
          // key-permuted column: s5=[i0,q1,q0,r1,r0] -> pos=[q1,q0,i0,r1,r0]
          const int pos = (s & ~31) | (quad * 8 + (i & 1) * 4 + r);
          out[(((size_t)(b * NH + h)) * DHD + dh) * S_LEN + pos] = v;
        }
      }
    }
  }
}

// ---------------- output projection GEMM -> f32 (R5 form) ------------------
__global__ __launch_bounds__(256) void gemm_out(const u16* __restrict__ A,
                                                const u16* __restrict__ Bw,
                                                float* __restrict__ out) {
  constexpr int K = 1024, N = 1024;
  __shared__ __align__(16) u16 Asm[2][128 * 32];
  __shared__ __align__(16) u16 Bsm[2][128 * 32];
  const int tid = threadIdx.x;
  const int wave = tid >> 6, lane = tid & 63;
  const int wm = wave >> 1, wn = wave & 1;
  const int quad = lane >> 4, l16 = lane & 15;
  const int m0 = blockIdx.y * 128, n0 = blockIdx.x * 128;
  const u16* Ag = A + (size_t)(m0 + (lane >> 2)) * K + (lane & 3) * 8;
  const u16* Bg = Bw + (size_t)(n0 + (lane >> 2)) * K + (lane & 3) * 8;

  auto STAGE = [&](int buf, int k0) {
#pragma unroll
    for (int c = 0; c < 2; ++c) {
      const int rbase = wave * 32 + c * 16;
      gld_lds16(Ag + (size_t)rbase * K + k0, Asm[buf] + rbase * 32);
      gld_lds16(Bg + (size_t)rbase * K + k0, Bsm[buf] + rbase * 32);
    }
  };

  f32x4 acc[4][4] = {};
  STAGE(0, 0);
  __syncthreads();
  int cur = 0;
  for (int k0 = 0; k0 < K; k0 += 32) {
    if (k0 + 32 < K) STAGE(cur ^ 1, k0 + 32);
    bf16x8 af[4], bfv[4];
#pragma unroll
    for (int i = 0; i < 4; ++i)
      af[i] = *(const bf16x8*)(Asm[cur] + (wm * 64 + i * 16 + l16) * 32 + quad * 8);
#pragma unroll
    for (int j = 0; j < 4; ++j)
      bfv[j] = *(const bf16x8*)(Bsm[cur] + (wn * 64 + j * 16 + l16) * 32 + quad * 8);
#pragma unroll
    for (int i = 0; i < 4; ++i)
#pragma unroll
      for (int j = 0; j < 4; ++j)
        acc[i][j] = __builtin_amdgcn_mfma_f32_16x16x32_bf16(af[i], bfv[j],
                                                            acc[i][j], 0, 0, 0);
    __syncthreads();
    cur ^= 1;
  }
#pragma unroll
  for (int i = 0; i < 4; ++i)
#pragma unroll
    for (int j = 0; j < 4; ++j)
#pragma unroll
      for (int r = 0; r < 4; ++r) {
        const int m = m0 + wm * 64 + i * 16 + quad * 4 + r;
        const int n = n0 + wn * 64 + j * 16 + l16;
        out[(size_t)m * N + n] = acc[i][j][r];
      }
}

// ---------------- causal flash attention (wave-split pairing) --------------
// grid (16, 32) = 512 blocks x 512 threads. XCD remap: xcd owns bh 4*xcd..+3.
// Waves 0-3 -> q-tile qtA=pairi (wave wl=wave&3 handles rows wl*16..+15);
// waves 4-7 -> q-tile qtB=31-pairi. Shared K/V staging (8 waves x 8 rows),
// 2-buffer prefetch-before-compute, 1 barrier/step. Each wave computes while
// t <= qt_own, masked at t == qt_own. V pre-permuted => V-read == K-read.
__global__ __launch_bounds__(512, 4) void attn_kernel(const u16* __restrict__ Qw,
                                                      const u16* __restrict__ Kw,
                                                      const u16* __restrict__ Vw,
                                                      u16* __restrict__ Ow) {
  __shared__ __align__(16) u16 Ksm[2][64 * 64];   // K rows [key][dh], swizzled
  __shared__ __align__(16) u16 Vsm[2][64 * 64];   // Vt rows [dh][key*], swizzled
  const int tid = threadIdx.x;
  const int wave = tid >> 6, lane = tid & 63;
  const int wl = wave & 3, wgrp = wave >> 2;
  const int quad = lane >> 4, l16 = lane & 15;
  const int flat = blockIdx.y * 16 + blockIdx.x;  // 512 blocks
  const int xcd = flat & 7, li = flat >> 3;       // li in 0..63
  const int bh = xcd * 4 + (li >> 4);
  const int pairi = li & 15;
  const int qtA = pairi, qtB = 31 - pairi;        // qtA < qtB always
  const int qt = wgrp ? qtB : qtA;                // this wave's q-tile
  const u16* Q = Qw + (size_t)bh * S_LEN * DHD;
  const u16* Kp = Kw + (size_t)bh * S_LEN * DHD;
  const u16* Vp = Vw + (size_t)bh * DHD * S_LEN;
  const int b = bh >> 4, h = bh & 15;

  const int ss = ((lane & 7) ^ (lane >> 3)) * 8;
  const int ps0 = (quad ^ (l16 & 7)) * 8;
  const int ps1 = ps0 ^ 32;

  const int qrow = qt * 64 + wl * 16 + l16;  // this lane's q-row
  const bf16x8 aq0 = *(const bf16x8*)(Q + (size_t)qrow * DHD + quad * 8);
  const bf16x8 aq1 = *(const bf16x8*)(Q + (size_t)qrow * DHD + 32 + quad * 8);

  f32x4 oacc[4] = {};
  float l4[4] = {0.f, 0.f, 0.f, 0.f};

  // 8 waves x 8 rows: wave covers K rows [wave*8, wave*8+8) and V rows same.
  auto stageKV = [&](int buf, int t) {
    const int k0 = t * 64;
    const int r0 = wave * 8;  // row&7 = lane>>3
    gld_lds16(Kp + (size_t)(k0 + r0 + (lane >> 3)) * DHD + ss,
              Ksm[buf] + r0 * 64);
    gld_lds16(Vp + (size_t)(r0 + (lane >> 3)) * S_LEN + k0 + ss,
              Vsm[buf] + r0 * 64);
  };

#define ATTN_TILE(T, MASK)                                                    \
  {                                                                           \
    const u16* Kc = Ksm[cur];                                                 \
    f32x4 sacc[4];                                                            \
    _Pragma("unroll") for (int nt = 0; nt < 4; ++nt) {                        \
      const u16* krow = Kc + (nt * 16 + l16) * 64;                            \
      const bf16x8 kb0 = *(const bf16x8*)(krow + ps0);                        \
      const bf16x8 kb1 = *(const bf16x8*)(krow + ps1);                        \
      f32x4 z = {};                                                           \
      z = __builtin_amdgcn_mfma_f32_16x16x32_bf16(kb0, aq0, z, 0, 0, 0);      \
      z = __builtin_amdgcn_mfma_f32_16x16x32_bf16(kb1, aq1, z, 0, 0, 0);      \
      sacc[nt] = z;                                                           \
    }                                                                         \
    u32 pw[8];                                                                \
    _Pragma("unroll") for (int nt = 0; nt < 4; ++nt) {                        \
      float p[4];                                                             \
      _Pragma("unroll") for (int r = 0; r < 4; ++r) {                         \
        float e = exp2f(sacc[nt][r] - SOFTMAX_M2);                            \
        if (MASK) {                                                           \
          const int col = (T) * 64 + nt * 16 + quad * 4 + r;                  \
          e = (col <= qrow) ? e : 0.f;                                        \
        }                                                                     \
        p[r] = e;                                                             \
        l4[r] += e;                                                           \
      }                                                                       \
      pw[nt * 2 + 0] = cvtpk(p[0], p[1]);                                     \
      pw[nt * 2 + 1] = cvtpk(p[2], p[3]);                                     \
    }                                                                         \
    const bf16x8 pa0 =                                                        \
        __builtin_bit_cast(bf16x8, (u32x4){pw[0], pw[1], pw[2], pw[3]});      \
    const bf16x8 pa1 =                                                        \
        __builtin_bit_cast(bf16x8, (u32x4){pw[4], pw[5], pw[6], pw[7]});      \
    const u16* Vc = Vsm[cur];                                                 \
    _Pragma("unroll") for (int nto = 0; nto < 4; ++nto) {                     \
      const u16* vrow = Vc + (nto * 16 + l16) * 64;                           \
      const bf16x8 bv0 = *(const bf16x8*)(vrow + ps0);                        \
      const bf16x8 bv1 = *(const bf16x8*)(vrow + ps1);                        \
      oacc[nto] =                                                             \
          __builtin_amdgcn_mfma_f32_16x16x32_bf16(pa0, bv0, oacc[nto], 0, 0, 0); \
      oacc[nto] =                                                             \
          __builtin_amdgcn_mfma_f32_16x16x32_bf16(pa1, bv1, oacc[nto], 0, 0, 0); \
    }                                                                         \
  }

  stageKV(0, 0);
  __syncthreads();
  int cur = 0;
  for (int t = 0; t < qtB; ++t) {
    stageKV(cur ^ 1, t + 1);           // prefetch before compute
    if (t <= qt) {                     // wave-uniform
      if (t == qt) {
        ATTN_TILE(t, 1)                // this wave's diagonal tile
      } else {
        ATTN_TILE(t, 0)
      }
    }
    __syncthreads();                   // prefetch drained + buffer reuse
    cur ^= 1;
  }
  if (qt == qtB) {                     // final tile: B group only, masked
    ATTN_TILE(qtB, 1)
  }
#undef ATTN_TILE

  // l reduction: lane's l4 is q-row l16's partial over its quad's keys
  float l = l4[0] + l4[1] + l4[2] + l4[3];
  l += __shfl_xor(l, 16);
  l += __shfl_xor(l, 32);              // full l for q-row l16, all lanes

  // epilogue -> [b, s, h, dh] bf16; oacc row quad*4+r = q-row base+quad*4+r
#pragma unroll
  for (int r = 0; r < 4; ++r) {
    const float inv = 1.f / __shfl(l, quad * 4 + r);
    const int s = qt * 64 + wl * 16 + quad * 4 + r;
#pragma unroll
    for (int nto = 0; nto < 4; ++nto) {
      const int dh = nto * 16 + l16;
      Ow[(((size_t)b * S_LEN + s) * NH + h) * DHD + dh] = f2bf(oacc[nto][r] * inv);
    }
  }
}

extern "C" void kernel_launch(void* const* d_in, const int* in_sizes, int n_in,
                              void* d_out, int out_size, void* d_ws, size_t ws_size,
                              hipStream_t stream) {
  const float* x  = (const float*)d_in[0];
  const float* wq = (const float*)d_in[1];
  const float* wk = (const float*)d_in[2];
  const float* wv = (const float*)d_in[3];
  const float* wo = (const float*)d_in[4];
  float* out = (float*)d_out;
  char* ws = (char*)d_ws;
  const size_t MB = 1024 * 1024;
  u16* xb  = (u16*)(ws);             // 8 MB  [4096][1024] bf16
  u16* wqb = (u16*)(ws + 8 * MB);    // 2 MB
  u16* wkb = (u16*)(ws + 10 * MB);   // 2 MB
  u16* wvb = (u16*)(ws + 12 * MB);   // 2 MB
  u16* wob = (u16*)(ws + 14 * MB);   // 2 MB
  u16* qws = (u16*)(ws + 16 * MB);   // 8 MB  [b,h,s,dh]
  u16* kws = (u16*)(ws + 24 * MB);   // 8 MB  [b,h,s,dh]
  u16* vws = (u16*)(ws + 32 * MB);   // 8 MB  [b,h,dh,s*] (key-permuted)
  u16* aws = (u16*)(ws + 40 * MB);   // 8 MB  [b,s,h,dh]

  cvt_all<<<8192, 256, 0, stream>>>(x, wq, wk, wv, wo, xb);
  gemm_qkv<<<dim3(24, 32), 256, 0, stream>>>(xb, wqb, wkb, wvb, qws, kws, vws);
  attn_kernel<<<dim3(16, 32), 512, 0, stream>>>(qws, kws, vws, aws);
  gemm_out<<<dim3(8, 32), 256, 0, stream>>>(aws, wob, out);
}